// Round 1
// baseline (216.846 us; speedup 1.0000x reference)
//
#include <hip/hip_runtime.h>

// ---------------------------------------------------------------------------
// Edge-conditioned kernel MLP, fully fused.
//   h1 = GELU(LN(edge @ W1 + b1));  h2 = GELU(LN(h1 @ W2 + b2))
//   k  = h2 @ W3 + b3  (128 -> 1024), out[e,o] = sum_i k[e,o*32+i] * x[e,i]
// 147456 edges, all GEMMs via mfma_f32_16x16x32_bf16 (fp32 accum).
// ---------------------------------------------------------------------------

typedef __bf16 bf16x8 __attribute__((ext_vector_type(8)));
typedef float f32x4 __attribute__((ext_vector_type(4)));
typedef unsigned short ushort8 __attribute__((ext_vector_type(8)));

#define N_EDGES 147456
#define TM 64
#define H_PITCH 132   // fp32 LDS pitch for 128 cols (+4 pad: conflict-free frag stores)

__device__ __forceinline__ unsigned short f2bf(float f) {
    unsigned u = __float_as_uint(f);
    u = u + 0x7FFFu + ((u >> 16) & 1u);   // RNE
    return (unsigned short)(u >> 16);
}

// Prep: W1,W2 (128x128) and W3 (128x1024) fp32 -> bf16, TRANSPOSED to [n][k]
// so MFMA B-fragments (n = lane&15, k contiguous x8) are 16B LDS reads.
__global__ void prep_weights(const float* __restrict__ W1,
                             const float* __restrict__ W2,
                             const float* __restrict__ W3,
                             unsigned short* __restrict__ ws) {
    int t = blockIdx.x * 256 + threadIdx.x;          // 163840 total
    if (t < 16384) {
        int k = t >> 7, n = t & 127;
        ws[n * 128 + k] = f2bf(W1[t]);
    } else if (t < 32768) {
        int j = t - 16384;
        int k = j >> 7, n = j & 127;
        ws[16384 + n * 128 + k] = f2bf(W2[j]);
    } else {
        int j = t - 32768;                           // j = k*1024 + n
        int k = j >> 10, n = j & 1023;
        ws[32768 + n * 128 + k] = f2bf(W3[j]);
    }
}

__global__ __launch_bounds__(256, 2)
void fused_edge_mlp(const float* __restrict__ edge, const float* __restrict__ x,
                    const float* __restrict__ b1, const float* __restrict__ g1,
                    const float* __restrict__ be1,
                    const float* __restrict__ b2, const float* __restrict__ g2,
                    const float* __restrict__ be2,
                    const float* __restrict__ b3,
                    const unsigned short* __restrict__ wsW,
                    float* __restrict__ out) {
    // sA: bf16 [64 rows][128 k], 256 B/row, XOR-swizzled. Holds edge, then h1, then h2.
    __shared__ __align__(16) unsigned char sA[TM * 256];          // 16 KB
    // sU: union { bf16 W-tile [128][128] swizzled (32 KB) | fp32 H [64][132] (33 KB) }
    __shared__ __align__(16) unsigned char sU[TM * H_PITCH * 4];  // 33792 B
    __shared__ float sX[TM * 33];                                 // x tile, padded

    float* sH = (float*)sU;

    const int t    = threadIdx.x;
    const int lane = t & 63;
    const int w    = t >> 6;          // wave id: owns N-strip [w*32, w*32+32)
    const int e0   = blockIdx.x * TM;

    const int mrow = lane & 15;
    const int swzl = (mrow & 7) << 4; // per-lane XOR (rows are mrow mod 16, &7 invariant)

    // ---- stage W-tile (bf16, swizzled) into sU ----
    auto stageB = [&](const unsigned short* srcW) {
#pragma unroll
        for (int i = 0; i < 8; i++) {
            int cid = t + i * 256;            // 2048 chunks of 16B
            int r = cid >> 4, kg = cid & 15;
            ushort8 u = *(const ushort8*)(srcW + r * 128 + kg * 8);
            *(ushort8*)(sU + r * 256 + ((kg * 16) ^ ((r & 7) << 4))) = u;
        }
    };

    // ---- one 64x(32-strip)x128 MFMA pass: A=sA, B=sU(W^T), per-wave 4x2 frags ----
    auto runMM = [&](f32x4 acc[4][2]) {
#pragma unroll
        for (int kk = 0; kk < 4; kk++) {
            int kb = kk * 64 + ((lane >> 4) << 4);   // byte offset of this lane's 8 k's
            bf16x8 a[4], b[2];
#pragma unroll
            for (int fm = 0; fm < 4; fm++)
                a[fm] = *(const bf16x8*)(sA + (fm * 16 + mrow) * 256 + (kb ^ swzl));
#pragma unroll
            for (int fn = 0; fn < 2; fn++) {
                int n = w * 32 + fn * 16 + mrow;
                b[fn] = *(const bf16x8*)(sU + n * 256 + (kb ^ swzl));
            }
#pragma unroll
            for (int fm = 0; fm < 4; fm++)
#pragma unroll
                for (int fn = 0; fn < 2; fn++)
                    acc[fm][fn] = __builtin_amdgcn_mfma_f32_16x16x32_bf16(
                        a[fm], b[fn], acc[fm][fn], 0, 0, 0);
        }
    };

    // ---- write frags (+bias) to fp32 sH. C/D layout: col=lane&15, row=(lane>>4)*4+r ----
    auto writeH = [&](f32x4 acc[4][2], const float* bias) {
        int rbase = (lane >> 4) * 4;
#pragma unroll
        for (int fn = 0; fn < 2; fn++) {
            int col = w * 32 + fn * 16 + mrow;
            float bv = bias ? bias[col] : 0.0f;
#pragma unroll
            for (int fm = 0; fm < 4; fm++)
#pragma unroll
                for (int r = 0; r < 4; r++)
                    sH[(fm * 16 + rbase + r) * H_PITCH + col] = acc[fm][fn][r] + bv;
        }
    };

    // ---- LN + exact GELU over sH rows, write bf16 (swizzled) into sA ----
    auto lnGelu = [&](const float* g, const float* be) {
        int row = w * 16 + (lane & 15);
        int q   = lane >> 4;                  // this lane covers cols [q*32, q*32+32)
        const float* hr = sH + row * H_PITCH + q * 32;
        float v[32];
        float s = 0.f, s2 = 0.f;
#pragma unroll
        for (int i = 0; i < 32; i++) { float f = hr[i]; v[i] = f; s += f; s2 += f * f; }
        s  += __shfl_xor(s, 16);  s  += __shfl_xor(s, 32);
        s2 += __shfl_xor(s2, 16); s2 += __shfl_xor(s2, 32);
        float mean = s * (1.0f / 128.0f);
        float var  = s2 * (1.0f / 128.0f) - mean * mean;
        float rs   = rsqrtf(var + 1e-5f);
        int rswz = (row & 7) << 4;
#pragma unroll
        for (int ii = 0; ii < 4; ii++) {
            ushort8 u;
#pragma unroll
            for (int j = 0; j < 8; j++) {
                int n = q * 32 + ii * 8 + j;
                float f = (v[ii * 8 + j] - mean) * rs * g[n] + be[n];
                f = 0.5f * f * (1.0f + erff(f * 0.70710678118f));   // exact GELU
                u[j] = f2bf(f);
            }
            *(ushort8*)(sA + row * 256 + ((q * 64 + ii * 16) ^ rswz)) = u;
        }
    };

    // ================= stage inputs =================
#pragma unroll
    for (int i = 0; i < 4; i++) {                    // edge tile -> sA (bf16, swizzled)
        int cid = t + i * 256;                       // 1024 chunks of 8 floats
        int r = cid >> 4, kg = cid & 15;
        const float4* src = (const float4*)(edge + (size_t)(e0 + r) * 128 + kg * 8);
        float4 v0 = src[0], v1 = src[1];
        ushort8 u;
        u[0] = f2bf(v0.x); u[1] = f2bf(v0.y); u[2] = f2bf(v0.z); u[3] = f2bf(v0.w);
        u[4] = f2bf(v1.x); u[5] = f2bf(v1.y); u[6] = f2bf(v1.z); u[7] = f2bf(v1.w);
        *(ushort8*)(sA + r * 256 + ((kg * 16) ^ ((r & 7) << 4))) = u;
    }
#pragma unroll
    for (int i = 0; i < 8; i++) {                    // x tile
        int idx = t + i * 256;
        int r = idx >> 5, c = idx & 31;
        sX[r * 33 + c] = x[(size_t)(e0 + r) * 32 + c];
    }
    stageB(wsW);                                     // W1^T
    __syncthreads();

    f32x4 acc[4][2];
    const f32x4 zz = {0.f, 0.f, 0.f, 0.f};

    // ================= layer 1 =================
#pragma unroll
    for (int i = 0; i < 4; i++) for (int j = 0; j < 2; j++) acc[i][j] = zz;
    runMM(acc);
    __syncthreads();                 // all waves done reading sU (W1) before sH overwrite
    writeH(acc, b1);
    __syncthreads();
    lnGelu(g1, be1);
    __syncthreads();                 // sH reads done; sA(h1) ready

    // ================= layer 2 =================
    stageB(wsW + 16384);             // W2^T
    __syncthreads();
#pragma unroll
    for (int i = 0; i < 4; i++) for (int j = 0; j < 2; j++) acc[i][j] = zz;
    runMM(acc);
    __syncthreads();
    writeH(acc, b2);
    __syncthreads();
    lnGelu(g2, be2);
    __syncthreads();

    // ================= layer 3 + per-edge GEMV, 8 N-chunks of 128 =================
    const int e_l = t >> 2, o_l = t & 3;
    for (int c = 0; c < 8; c++) {
        stageB(wsW + 32768 + c * 16384);             // W3^T rows [c*128, c*128+128)
        __syncthreads();
#pragma unroll
        for (int i = 0; i < 4; i++) for (int j = 0; j < 2; j++) acc[i][j] = zz;
        runMM(acc);
        __syncthreads();
        writeH(acc, nullptr);
        __syncthreads();
        // out[e, o] = sum_i (k[e, o*32+i] + b3[o*32+i]) * x[e, i], o = c*4 + o_l
        {
            const float* kr  = sH + e_l * H_PITCH + o_l * 32;
            const float* xr  = sX + e_l * 33;
            const float* b3r = b3 + (c * 4 + o_l) * 32;
            float sum = 0.f;
#pragma unroll
            for (int i = 0; i < 32; i++) sum += (kr[i] + b3r[i]) * xr[i];
            out[(size_t)(e0 + e_l) * 32 + c * 4 + o_l] = sum;
        }
        __syncthreads();                             // sH free for next chunk's W tile
    }
}

extern "C" void kernel_launch(void* const* d_in, const int* in_sizes, int n_in,
                              void* d_out, int out_size, void* d_ws, size_t ws_size,
                              hipStream_t stream) {
    const float* x    = (const float*)d_in[0];
    const float* edge = (const float*)d_in[1];
    const float* W1   = (const float*)d_in[2];
    const float* b1   = (const float*)d_in[3];
    const float* g1   = (const float*)d_in[4];
    const float* be1  = (const float*)d_in[5];
    const float* W2   = (const float*)d_in[6];
    const float* b2   = (const float*)d_in[7];
    const float* g2   = (const float*)d_in[8];
    const float* be2  = (const float*)d_in[9];
    const float* W3   = (const float*)d_in[10];
    const float* b3   = (const float*)d_in[11];
    unsigned short* wsW = (unsigned short*)d_ws;     // 320 KB: W1^T | W2^T | W3^T (bf16)
    float* outp = (float*)d_out;

    prep_weights<<<640, 256, 0, stream>>>(W1, W2, W3, wsW);
    fused_edge_mlp<<<N_EDGES / TM, 256, 0, stream>>>(
        edge, x, b1, g1, be1, b2, g2, be2, b3, wsW, outp);
}

// Round 4
// 182.180 us; speedup vs baseline: 1.1903x; 1.1903x over previous
//
#include <hip/hip_runtime.h>

// ---------------------------------------------------------------------------
// Edge-conditioned kernel MLP, fully fused. R4: revert to R1's verified
// numerics/layouts; restructure waves as 16-row x 128-col tiles (fm=1,fn=8)
// so LN + layer-3 GEMV are wave-local (no fp32 H LDS region, no GEMV LDS
// reads, 19 barriers). LDS 51KB -> 3 blocks/CU (12 waves/CU).
// ---------------------------------------------------------------------------

typedef __bf16 bf16x8 __attribute__((ext_vector_type(8)));
typedef float f32x4 __attribute__((ext_vector_type(4)));
typedef unsigned short ushort8 __attribute__((ext_vector_type(8)));

#define N_EDGES 147456
#define TM 64

__device__ __forceinline__ unsigned short f2bf(float f) {
    unsigned u = __float_as_uint(f);
    u = u + 0x7FFFu + ((u >> 16) & 1u);   // RNE
    return (unsigned short)(u >> 16);
}

// Prep (R1 verbatim): W1,W2 (128x128), W3 (128x1024) fp32 -> bf16 W^T [n][k].
__global__ void prep_weights(const float* __restrict__ W1,
                             const float* __restrict__ W2,
                             const float* __restrict__ W3,
                             unsigned short* __restrict__ ws) {
    int t = blockIdx.x * 256 + threadIdx.x;          // 163840 total
    if (t < 16384) {
        int k = t >> 7, n = t & 127;
        ws[n * 128 + k] = f2bf(W1[t]);
    } else if (t < 32768) {
        int j = t - 16384;
        int k = j >> 7, n = j & 127;
        ws[16384 + n * 128 + k] = f2bf(W2[j]);
    } else {
        int j = t - 32768;                           // j = k*1024 + n
        int k = j >> 10, n = j & 1023;
        ws[32768 + n * 128 + k] = f2bf(W3[j]);       // [n][k], n-major
    }
}

__global__ __launch_bounds__(256, 3)
void fused_edge_mlp(const float* __restrict__ edge, const float* __restrict__ x,
                    const float* __restrict__ b1, const float* __restrict__ g1,
                    const float* __restrict__ be1,
                    const float* __restrict__ b2, const float* __restrict__ g2,
                    const float* __restrict__ be2,
                    const float* __restrict__ b3,
                    const unsigned short* __restrict__ wsW,
                    float* __restrict__ out) {
    // sA: bf16 [64 rows][128 k], 256B/row, XOR-swizzled (slot ^ (row&7)).
    __shared__ __align__(16) unsigned char sA[TM * 256];       // 16 KB
    // sW: bf16 W^T tile [128 n][128 k], swizzled same scheme.
    __shared__ __align__(16) unsigned char sW[128 * 256];      // 32 KB
    __shared__ float sGB[768];  // b1|g1|be1|b2|g2|be2, 128 each     3 KB

    const int t    = threadIdx.x;
    const int lane = t & 63;
    const int w    = t >> 6;          // wave: owns edge-rows [w*16, w*16+16)
    const int e0   = blockIdx.x * TM;
    const int mrow = lane & 15;       // MFMA col lane (feature)
    const int hi   = lane >> 4;       // MFMA row group / k-group
    const int swzl = (mrow & 7) << 4;

    // ---- stage W tile (R1's stageB verbatim, into sW) ----
    auto stageB = [&](const unsigned short* srcW) {
#pragma unroll
        for (int i = 0; i < 8; i++) {
            int cid = t + i * 256;            // 2048 x 16B chunks
            int r = cid >> 4, kg = cid & 15;
            ushort8 u = *(const ushort8*)(srcW + r * 128 + kg * 8);
            *(ushort8*)(sW + r * 256 + ((kg * 16) ^ ((r & 7) << 4))) = u;
        }
    };

    // ---- MFMA: wave's 16 rows x 128 cols, K=128. acc[fn] col-block fn*16 ----
    auto runMM = [&](f32x4 (&acc)[8]) {
#pragma unroll
        for (int kk = 0; kk < 4; kk++) {
            int kb = kk * 64 + (hi << 4);
            bf16x8 a = *(const bf16x8*)(sA + (w * 16 + mrow) * 256 + (kb ^ swzl));
#pragma unroll
            for (int fn = 0; fn < 8; fn++) {
                bf16x8 b = *(const bf16x8*)(sW + (fn * 16 + mrow) * 256 + (kb ^ swzl));
                acc[fn] = __builtin_amdgcn_mfma_f32_16x16x32_bf16(a, b, acc[fn], 0, 0, 0);
            }
        }
    };
    // C/D layout: col = fn*16 + mrow, row(edge) = w*16 + hi*4 + rr.

    // ---- wave-local LN + exact GELU; write h bf16 into OWN sA rows ----
    auto lnGelu = [&](f32x4 (&acc)[8], const float* bb, const float* gg,
                      const float* ee) {
        float bc[8], gc[8], ec[8];
#pragma unroll
        for (int fn = 0; fn < 8; fn++) {
            int col = fn * 16 + mrow;
            bc[fn] = bb[col]; gc[fn] = gg[col]; ec[fn] = ee[col];
        }
        float mean[4], rsv[4];
#pragma unroll
        for (int rr = 0; rr < 4; rr++) {
            float s = 0.f, s2 = 0.f;
#pragma unroll
            for (int fn = 0; fn < 8; fn++) {
                float v = acc[fn][rr] + bc[fn];
                s += v; s2 += v * v;
            }
            s  += __shfl_xor(s, 1);  s  += __shfl_xor(s, 2);
            s  += __shfl_xor(s, 4);  s  += __shfl_xor(s, 8);
            s2 += __shfl_xor(s2, 1); s2 += __shfl_xor(s2, 2);
            s2 += __shfl_xor(s2, 4); s2 += __shfl_xor(s2, 8);
            mean[rr] = s * (1.0f / 128.0f);
            float var = s2 * (1.0f / 128.0f) - mean[rr] * mean[rr];
            rsv[rr] = rsqrtf(var + 1e-5f);
        }
#pragma unroll
        for (int rr = 0; rr < 4; rr++) {
            int R = w * 16 + hi * 4 + rr;
            int rsw = (R & 7) << 4;
#pragma unroll
            for (int fn = 0; fn < 8; fn++) {
                float v = acc[fn][rr] + bc[fn];
                float f = (v - mean[rr]) * rsv[rr] * gc[fn] + ec[fn];
                f = 0.5f * f * (1.0f + erff(f * 0.70710678118f));   // exact GELU
                *(unsigned short*)(sA + R * 256 + ((fn * 32 + mrow * 2) ^ rsw))
                    = f2bf(f);
            }
        }
    };

    // ---- layer-3 GEMV, fully in-wave: out[R][c*4+o] from acc + b3 + x regs ----
    auto gemv = [&](f32x4 (&acc)[8], int c, const float (&xlo)[4],
                    const float (&xhi)[4]) {
        float b3v[8];
#pragma unroll
        for (int fn = 0; fn < 8; fn++)
            b3v[fn] = b3[c * 128 + fn * 16 + mrow];
#pragma unroll
        for (int o = 0; o < 4; o++) {
#pragma unroll
            for (int rr = 0; rr < 4; rr++) {
                float p = (acc[2*o][rr]   + b3v[2*o])   * xlo[rr]
                        + (acc[2*o+1][rr] + b3v[2*o+1]) * xhi[rr];
                p += __shfl_xor(p, 1); p += __shfl_xor(p, 2);
                p += __shfl_xor(p, 4); p += __shfl_xor(p, 8);
                if (mrow == 0)
                    out[(size_t)(e0 + w * 16 + hi * 4 + rr) * 32 + c * 4 + o] = p;
            }
        }
    };

    // ================= prologue =================
#pragma unroll
    for (int i = 0; i < 4; i++) {                    // edge -> sA (R1 verbatim)
        int cid = t + i * 256;                       // 1024 chunks of 8 floats
        int r = cid >> 4, kg = cid & 15;
        const float* src = edge + (size_t)(e0 + r) * 128 + kg * 8;
        float4 v0 = *(const float4*)src, v1 = *(const float4*)(src + 4);
        ushort8 u;
        u[0] = f2bf(v0.x); u[1] = f2bf(v0.y); u[2] = f2bf(v0.z); u[3] = f2bf(v0.w);
        u[4] = f2bf(v1.x); u[5] = f2bf(v1.y); u[6] = f2bf(v1.z); u[7] = f2bf(v1.w);
        *(ushort8*)(sA + r * 256 + ((kg * 16) ^ ((r & 7) << 4))) = u;
    }
    float xlo[4], xhi[4];
#pragma unroll
    for (int rr = 0; rr < 4; rr++) {                 // x for this lane's rows
        size_t xb = (size_t)(e0 + w * 16 + hi * 4 + rr) * 32;
        xlo[rr] = x[xb + mrow];
        xhi[rr] = x[xb + mrow + 16];
    }
    {   // LN params -> sGB: b1|g1|be1|b2|g2|be2
        int c0 = t & 127;
        sGB[t]       = (t < 128)       ? b1[c0] : g1[c0];
        sGB[256 + t] = (t < 128)       ? be1[c0] : b2[c0];
        sGB[512 + t] = (t < 128)       ? g2[c0] : be2[c0];
    }
    stageB(wsW);                                     // W1
    __syncthreads();

    f32x4 acc[8];
    const f32x4 zz = {0.f, 0.f, 0.f, 0.f};

    // ================= layer 1 =================
#pragma unroll
    for (int i = 0; i < 8; i++) acc[i] = zz;
    runMM(acc);                        // reads own sA rows + sW(W1)
    lnGelu(acc, sGB, sGB + 128, sGB + 256);   // writes OWN sA rows (no barrier)
    __syncthreads();                   // all waves done reading sW(W1)
    stageB(wsW + 16384);               // W2
    __syncthreads();

    // ================= layer 2 =================
#pragma unroll
    for (int i = 0; i < 8; i++) acc[i] = zz;
    runMM(acc);
    lnGelu(acc, sGB + 384, sGB + 512, sGB + 640);
    __syncthreads();
    stageB(wsW + 32768);               // W3 chunk 0
    __syncthreads();

    // ================= layer 3: 8 chunks of 128 cols + in-wave GEMV ==========
    for (int c = 0; c < 8; c++) {
#pragma unroll
        for (int i = 0; i < 8; i++) acc[i] = zz;
        runMM(acc);                    // reads own sA(h2) + sW(W3c)
        gemv(acc, c, xlo, xhi);        // registers + shfl only
        if (c < 7) {
            __syncthreads();           // sW reads done
            stageB(wsW + 32768 + (size_t)(c + 1) * 16384);
            __syncthreads();
        }
    }
}

extern "C" void kernel_launch(void* const* d_in, const int* in_sizes, int n_in,
                              void* d_out, int out_size, void* d_ws, size_t ws_size,
                              hipStream_t stream) {
    const float* x    = (const float*)d_in[0];
    const float* edge = (const float*)d_in[1];
    const float* W1   = (const float*)d_in[2];
    const float* b1   = (const float*)d_in[3];
    const float* g1   = (const float*)d_in[4];
    const float* be1  = (const float*)d_in[5];
    const float* W2   = (const float*)d_in[6];
    const float* b2   = (const float*)d_in[7];
    const float* g2   = (const float*)d_in[8];
    const float* be2  = (const float*)d_in[9];
    const float* W3   = (const float*)d_in[10];
    const float* b3   = (const float*)d_in[11];
    unsigned short* wsW = (unsigned short*)d_ws;     // 320 KB: W1^T|W2^T|W3^T bf16
    float* outp = (float*)d_out;

    prep_weights<<<640, 256, 0, stream>>>(W1, W2, W3, wsW);
    fused_edge_mlp<<<N_EDGES / TM, 256, 0, stream>>>(
        edge, x, b1, g1, be1, b2, g2, be2, b3, wsW, outp);
}